// Round 4
// baseline (1134.160 us; speedup 1.0000x reference)
//
#include <hip/hip_runtime.h>
#include <stdint.h>

#define NN 50000
#define EE 800000
#define DH 128
#define NC 40
#define KCAT (14*DH)   // 1792
#define CAP 64         // ELL capacity; deg ~ Binom(800k,1/50k), P(deg>64) ~ 1e-18

typedef __bf16 bf16x8 __attribute__((ext_vector_type(8)));
typedef float floatx4 __attribute__((ext_vector_type(4)));

// async global->LDS, 16B per lane, linear dest (wave-uniform base + lane*16)
#define GLOAD_LDS16(gp, lp)                                                          \
  __builtin_amdgcn_global_load_lds(                                                  \
      (const __attribute__((address_space(1))) uint32_t*)(gp),                       \
      (__attribute__((address_space(3))) uint32_t*)(lp), 16, 0, 0)

__device__ __forceinline__ float bf2f(unsigned short u) {
  union { uint32_t i; float f; } v; v.i = ((uint32_t)u) << 16; return v.f;
}
__device__ __forceinline__ unsigned short f2bf(float f) {
  union { float f; uint32_t i; } v; v.f = f;
  uint32_t x = v.i;
  uint32_t r = (x + 0x7fffu + ((x >> 16) & 1u)) >> 16;  // RNE
  return (unsigned short)r;
}

// ---------------- setup: zero ELL counts + dtype detect (merged) ----------------
__global__ void init_counts_detect(int* counts, const unsigned short* xw) {
  int i = blockIdx.x * blockDim.x + threadIdx.x;
  if (i < NN) counts[i] = 0;
  if (blockIdx.x == 0) {
    int t = threadIdx.x;
    int wild = 0;
    for (int k = t; k < 4096; k += 256) {
      unsigned e = (xw[k] >> 7) & 0xFF;
      if (e >= 0x90) wild++;
    }
    __shared__ int red[256];
    red[t] = wild;
    __syncthreads();
    for (int s = 128; s > 0; s >>= 1) {
      if (t < s) red[t] += red[t + s];
      __syncthreads();
    }
    if (t == 0) counts[NN] = red[0];  // flag slot
  }
}

// vectorized dtype convert (n must be divisible by 4)
__global__ void convert_f4(const void* in, unsigned short* outp, int n4, const int* flag) {
  bool isf32 = (*flag) > 32;
  for (int i = blockIdx.x * blockDim.x + threadIdx.x; i < n4;
       i += gridDim.x * blockDim.x) {
    ushort4 o;
    if (isf32) {
      float4 v = ((const float4*)in)[i];
      o.x = f2bf(v.x); o.y = f2bf(v.y); o.z = f2bf(v.z); o.w = f2bf(v.w);
    } else {
      o = ((const ushort4*)in)[i];
    }
    ((ushort4*)outp)[i] = o;
  }
}

// all four bias vectors in one launch; bb layout: b0[128] b1[128] bm[1664] b15[40]
__global__ void convert_bias(const void* b0, const void* b1, const void* bm,
                             const void* b15, unsigned short* bb, const int* flag) {
  bool isf32 = (*flag) > 32;
  int i = blockIdx.x * blockDim.x + threadIdx.x;
  if (i >= 1960) return;
  const void* src; int off;
  if (i < 128)        { src = b0;  off = i; }
  else if (i < 256)   { src = b1;  off = i - 128; }
  else if (i < 1920)  { src = bm;  off = i - 256; }
  else                { src = b15; off = i - 1920; }
  bb[i] = isf32 ? f2bf(((const float*)src)[off]) : ((const unsigned short*)src)[off];
}

// B[L][K][M] -> BT[L][Mpad][K] (bf16 out), zero-pad n>=M
__global__ void transpose_w(const void* B, unsigned short* BT,
                            int L, int K, int M, int Mpad, const int* flag) {
  bool isf32 = (*flag) > 32;
  int total = L * Mpad * K;
  for (int idx = blockIdx.x * blockDim.x + threadIdx.x; idx < total;
       idx += gridDim.x * blockDim.x) {
    int k = idx % K;
    int n = (idx / K) % Mpad;
    int l = idx / (K * Mpad);
    unsigned short v = 0;
    if (n < M) {
      size_t si = (size_t)l * K * M + (size_t)k * M + n;
      v = isf32 ? f2bf(((const float*)B)[si]) : ((const unsigned short*)B)[si];
    }
    BT[idx] = v;
  }
}

// ---------------- ELL adjacency build ----------------
__global__ void build_ell(const int* __restrict__ src, const int* __restrict__ dst,
                          const void* __restrict__ w,
                          int* __restrict__ cnt, int2* __restrict__ ell,
                          const int* __restrict__ flag) {
  bool isf32 = (*flag) > 32;
  int e = blockIdx.x * blockDim.x + threadIdx.x;
  if (e >= EE) return;
  int d = dst[e];
  if ((unsigned)d >= NN) return;
  int p = atomicAdd(&cnt[d], 1);
  if (p >= CAP) return;
  int s = src[e];
  float wf = isf32 ? ((const float*)w)[e] : bf2f(((const unsigned short*)w)[e]);
  if ((unsigned)s >= NN) { s = 0; wf = 0.f; }
  union { float f; int i; } wv; wv.f = wf;
  ell[(size_t)d * CAP + p] = make_int2(s, wv.i);
}

// pad each row's slots to a multiple of 8 with zero-weight edges
__global__ void pad_ell(const int* __restrict__ cnt, int2* __restrict__ ell) {
  int wave = threadIdx.x >> 6, lane = threadIdx.x & 63;
  int row = blockIdx.x * 4 + wave;
  if (row >= NN) return;
  int n = cnt[row];
  if (n > CAP) n = CAP;
  int padn = (n + 7) & ~7;
  if (lane >= n && lane < padn) ell[(size_t)row * CAP + lane] = make_int2(0, 0);
}

// ============ first GEMM pair: z = x@W0+b0, supp = x@W1 (K=256, 256 cols) ============
__global__ __launch_bounds__(256) void gemm_first(
    const unsigned short* __restrict__ A,    // xbf [N][256]
    const unsigned short* __restrict__ BT,   // [256][256]: rows 0-127=W0T, 128-255=W1T
    unsigned short* __restrict__ C0,         // zbuf [N][128]  (+bias)
    unsigned short* __restrict__ C1,         // supp [N][128]
    const unsigned short* __restrict__ bias) {
  __shared__ unsigned short As[64 * 256];    // 32KB, row stride 512B, swizzled
  int t = threadIdx.x;
  int wave = t >> 6, lane = t & 63;
  int q = lane >> 4, mn = lane & 15;
  int r0 = blockIdx.x * 64;

  #pragma unroll
  for (int cc = 0; cc < 8; ++cc) {
    int L = cc * 4096 + t * 16;
    int row = L >> 9;
    int colb = (L & 511) ^ ((row & 7) << 4);
    int gr = r0 + row; if (gr >= NN) gr = NN - 1;
    GLOAD_LDS16((const char*)A + (size_t)gr * 512 + colb, (char*)As + L);
  }
  __syncthreads();

  floatx4 acc[4][4];
  floatx4 zf = {0.f, 0.f, 0.f, 0.f};
  #pragma unroll
  for (int i = 0; i < 4; ++i)
    #pragma unroll
    for (int j = 0; j < 4; ++j) acc[i][j] = zf;

  #pragma unroll
  for (int ks = 0; ks < 8; ++ks) {
    bf16x8 fa[4], fb[4];
    #pragma unroll
    for (int i = 0; i < 4; ++i) {
      int row = i * 16 + mn;
      fa[i] = *(const bf16x8*)((const char*)As + row * 512 +
                               ((ks * 64 + q * 16) ^ ((row & 7) << 4)));
    }
    #pragma unroll
    for (int j = 0; j < 4; ++j)
      fb[j] = *(const bf16x8*)((const char*)BT +
                               (size_t)(wave * 64 + j * 16 + mn) * 512 + ks * 64 + q * 16);
    #pragma unroll
    for (int i = 0; i < 4; ++i)
      #pragma unroll
      for (int j = 0; j < 4; ++j)
        acc[i][j] = __builtin_amdgcn_mfma_f32_16x16x32_bf16(fa[i], fb[j], acc[i][j], 0, 0, 0);
  }

  #pragma unroll
  for (int j = 0; j < 4; ++j) {
    int col = wave * 64 + j * 16 + mn;
    bool is0 = col < 128;
    int ccol = is0 ? col : col - 128;
    unsigned short* Cp = is0 ? C0 : C1;
    float badd = is0 ? bf2f(bias[ccol]) : 0.f;
    #pragma unroll
    for (int i = 0; i < 4; ++i) {
      int rbase = r0 + i * 16 + q * 4;
      #pragma unroll
      for (int rr = 0; rr < 4; ++rr) {
        int row = rbase + rr;
        if (row < NN) Cp[(size_t)row * 128 + ccol] = f2bf(acc[i][j][rr] + badd);
      }
    }
  }
}

// ============ mid GEMM: supp[N,128] = x_l[N(,KCAT stride)][128] @ B ============
__global__ __launch_bounds__(256) void gemm_mid(
    const unsigned short* __restrict__ A,    // row stride KCAT
    const unsigned short* __restrict__ BT,   // [128][128]
    unsigned short* __restrict__ C) {        // supp [N][128]
  __shared__ unsigned short As[32 * 128];    // 8KB, row stride 256B, swizzled
  int t = threadIdx.x;
  int wave = t >> 6, lane = t & 63;
  int q = lane >> 4, mn = lane & 15;
  int r0 = blockIdx.x * 32;

  #pragma unroll
  for (int cc = 0; cc < 2; ++cc) {
    int L = cc * 4096 + t * 16;
    int row = L >> 8;
    int colb = (L & 255) ^ ((row & 7) << 4);
    int gr = r0 + row; if (gr >= NN) gr = NN - 1;
    GLOAD_LDS16((const char*)A + (size_t)gr * (KCAT * 2) + colb, (char*)As + L);
  }
  __syncthreads();

  floatx4 acc[2][2];
  floatx4 zf = {0.f, 0.f, 0.f, 0.f};
  #pragma unroll
  for (int i = 0; i < 2; ++i)
    #pragma unroll
    for (int j = 0; j < 2; ++j) acc[i][j] = zf;

  #pragma unroll
  for (int ks = 0; ks < 4; ++ks) {
    bf16x8 fa[2], fb[2];
    #pragma unroll
    for (int i = 0; i < 2; ++i) {
      int row = i * 16 + mn;
      fa[i] = *(const bf16x8*)((const char*)As + row * 256 +
                               ((ks * 64 + q * 16) ^ ((row & 7) << 4)));
    }
    #pragma unroll
    for (int j = 0; j < 2; ++j)
      fb[j] = *(const bf16x8*)((const char*)BT +
                               (size_t)(wave * 32 + j * 16 + mn) * 256 + ks * 64 + q * 16);
    #pragma unroll
    for (int i = 0; i < 2; ++i)
      #pragma unroll
      for (int j = 0; j < 2; ++j)
        acc[i][j] = __builtin_amdgcn_mfma_f32_16x16x32_bf16(fa[i], fb[j], acc[i][j], 0, 0, 0);
  }

  #pragma unroll
  for (int i = 0; i < 2; ++i) {
    int rbase = r0 + i * 16 + q * 4;
    #pragma unroll
    for (int j = 0; j < 2; ++j) {
      int col = wave * 32 + j * 16 + mn;
      #pragma unroll
      for (int rr = 0; rr < 4; ++rr) {
        int row = rbase + rr;
        if (row < NN) C[(size_t)row * 128 + col] = f2bf(acc[i][j][rr]);
      }
    }
  }
}

// ============ final GEMM: s15[N,40] = xcat[N,1792] @ W15 (fp32 out) ============
// T3/T4 structure: 4 LDS buffers, prefetch distance 3, raw s_barrier + counted
// vmcnt (never 0 in steady state). Per-iter issue order: [wait|barrier|compute(c)
// |loadB(c+1)|stage(c+3)] so the wait before compute(c) only needs vmcnt(4):
// everything newer than fb(c) is stage(c+2) (4 loads). Stages fly 2-3 iters.
// Buffer reuse safe: stage(c+3) hits As[(c+3)&3], whose last reader (compute(c-1))
// finished before barrier(c), which precedes this stage in every wave's program order.
__global__ __launch_bounds__(256) void gemm_cat4(
    const unsigned short* __restrict__ A,    // xcat [N][1792]
    const unsigned short* __restrict__ BT,   // [48][1792]
    float* __restrict__ C) {
  __shared__ unsigned short As[4][64 * 128]; // 4 x 16KB = 64KB, row stride 256B, swizzled
  int t = threadIdx.x;
  int wave = t >> 6, lane = t & 63;
  int q = lane >> 4, mn = lane & 15;
  int r0 = blockIdx.x * 64;

  floatx4 acc[3];
  floatx4 zf = {0.f, 0.f, 0.f, 0.f};
  #pragma unroll
  for (int j = 0; j < 3; ++j) acc[j] = zf;

  const char* bbase[3];
  #pragma unroll
  for (int j = 0; j < 3; ++j)
    bbase[j] = (const char*)BT + (size_t)(j * 16 + mn) * 3584 + q * 16;

  auto stage = [&](int c) {
    #pragma unroll
    for (int cc = 0; cc < 4; ++cc) {
      int L = cc * 4096 + t * 16;
      int row = L >> 8;
      int colb = (L & 255) ^ ((row & 7) << 4);
      int gr = r0 + row; if (gr >= NN) gr = NN - 1;
      GLOAD_LDS16((const char*)A + (size_t)gr * 3584 + c * 256 + colb,
                  (char*)As[c & 3] + L);
    }
  };

  bf16x8 fb[3][4];
  auto loadB = [&](int c) {
    #pragma unroll
    for (int ks = 0; ks < 4; ++ks)
      #pragma unroll
      for (int j = 0; j < 3; ++j)
        fb[j][ks] = *(const bf16x8*)(bbase[j] + c * 256 + ks * 64);
  };

  // prologue; compile fences pin FIFO order: [s0 | fb0 | s1 | s2]
  stage(0);
  asm volatile("" ::: "memory");
  loadB(0);
  asm volatile("" ::: "memory");
  stage(1);
  stage(2);

  int rloc = wave * 16 + mn;
  int rsw = (rloc & 7) << 4;
  for (int c = 0; c < 14; ++c) {
    if (c == 0)      asm volatile("s_waitcnt vmcnt(8)" ::: "memory");
    else if (c < 12) asm volatile("s_waitcnt vmcnt(4)" ::: "memory");
    else             asm volatile("s_waitcnt vmcnt(0)" ::: "memory");
    __builtin_amdgcn_s_barrier();
    const char* buf = (const char*)As[c & 3];
    #pragma unroll
    for (int ks = 0; ks < 4; ++ks) {
      bf16x8 fa = *(const bf16x8*)(buf + rloc * 256 + ((ks * 64 + q * 16) ^ rsw));
      #pragma unroll
      for (int j = 0; j < 3; ++j)
        acc[j] = __builtin_amdgcn_mfma_f32_16x16x32_bf16(fa, fb[j][ks], acc[j], 0, 0, 0);
    }
    asm volatile("" ::: "memory");
    if (c + 1 < 14) loadB(c + 1);
    asm volatile("" ::: "memory");
    if (c + 3 < 14) stage(c + 3);
  }

  #pragma unroll
  for (int j = 0; j < 3; ++j) {
    int col = j * 16 + mn;
    if (col < NC) {
      #pragma unroll
      for (int rr = 0; rr < 4; ++rr) {
        int row = r0 + wave * 16 + q * 4 + rr;
        if (row < NN) C[(size_t)row * NC + col] = acc[j][rr];
      }
    }
  }
}

// ---------------- SPMM fused, XCD-sliced: out = relu(agg + b) + res ----------------
// 4 column-slices of 32 cols (64B): slice = blockIdx&3. Under round-robin
// workgroup->XCD dispatch, XCD k only touches slice k%4, so the per-XCD gather
// working set is 3.2MB (< 4MB L2) -> gathers become L2-hits instead of L3.
// Wave = 4 rows x 16 lanes; each lane holds 4 ELL slots (static-indexed);
// loop bound = wave-max padn (padded slots have s=0,w=0 -> hot-line dummy gathers).
// Per-output summation order identical to the unsliced kernel.
__global__ __launch_bounds__(256) void spmm_layer_sliced(
    const unsigned short* __restrict__ support, const int* __restrict__ cnt,
    const int2* __restrict__ ell, const unsigned short* __restrict__ bias,
    const unsigned short* __restrict__ res, int res_stride,
    unsigned short* __restrict__ out, int out_stride) {
  int bid = blockIdx.x;
  int slice = bid & 3;
  int rblk = bid >> 2;                       // 0..3124 (NN = 16*3125 exactly)
  int wave = threadIdx.x >> 6, lane = threadIdx.x & 63;
  int group = lane >> 4, gl = lane & 15;
  int row = rblk * 16 + wave * 4 + group;
  int colb = slice * 64 + gl * 4;            // byte offset within 256B feature row

  int n = cnt[row]; if (n > CAP) n = CAP;
  int padn = (n + 7) & ~7;
  const int2* erow = ell + (size_t)row * CAP;
  int2 ev0 = (gl      < padn) ? erow[gl]      : make_int2(0, 0);
  int2 ev1 = (gl + 16 < padn) ? erow[gl + 16] : make_int2(0, 0);
  int2 ev2 = (gl + 32 < padn) ? erow[gl + 32] : make_int2(0, 0);
  int2 ev3 = (gl + 48 < padn) ? erow[gl + 48] : make_int2(0, 0);

  int wm = padn;                              // wave-uniform max over 4 groups
  wm = max(wm, __shfl_xor(wm, 16));
  wm = max(wm, __shfl_xor(wm, 32));

  int srcbase = lane & 0x30;                  // group*16
  float a0 = 0.f, a1 = 0.f;
  uint32_t gA[8], gB[8];

  auto load8 = [&](uint32_t* g, int2 EV, int boff) {
    #pragma unroll
    for (int u = 0; u < 8; ++u) {
      int s = __shfl(EV.x, srcbase + boff + u);
      g[u] = *(const uint32_t*)((const char*)support + (size_t)s * 256 + colb);
    }
  };
  auto fma8 = [&](const uint32_t* g, int2 EV, int boff) {
    #pragma unroll
    for (int u = 0; u < 8; ++u) {
      union { int i; float f; } wv; wv.i = __shfl(EV.y, srcbase + boff + u);
      a0 += wv.f * bf2f((unsigned short)(g[u] & 0xffff));
      a1 += wv.f * bf2f((unsigned short)(g[u] >> 16));
    }
  };

  if (wm > 0) {
    load8(gA, ev0, 0);
    if (wm > 8)  load8(gB, ev0, 8);
    fma8(gA, ev0, 0);
    if (wm > 8)  { if (wm > 16) load8(gA, ev1, 0); fma8(gB, ev0, 8); }
    if (wm > 16) { if (wm > 24) load8(gB, ev1, 8); fma8(gA, ev1, 0); }
    if (wm > 24) { if (wm > 32) load8(gA, ev2, 0); fma8(gB, ev1, 8); }
    if (wm > 32) { if (wm > 40) load8(gB, ev2, 8); fma8(gA, ev2, 0); }
    if (wm > 40) { if (wm > 48) load8(gA, ev3, 0); fma8(gB, ev2, 8); }
    if (wm > 48) { if (wm > 56) load8(gB, ev3, 8); fma8(gA, ev3, 0); }
    if (wm > 56) fma8(gB, ev3, 8);
  }

  uint32_t bw = *(const uint32_t*)((const char*)bias + colb);
  uint32_t rw = *(const uint32_t*)((const char*)res + (size_t)row * res_stride * 2 + colb);
  float v0 = fmaxf(a0 + bf2f((unsigned short)(bw & 0xffff)), 0.f) +
             bf2f((unsigned short)(rw & 0xffff));
  float v1 = fmaxf(a1 + bf2f((unsigned short)(bw >> 16)), 0.f) +
             bf2f((unsigned short)(rw >> 16));
  uint32_t o = (uint32_t)f2bf(v0) | ((uint32_t)f2bf(v1) << 16);
  *(uint32_t*)((char*)out + (size_t)row * out_stride * 2 + colb) = o;
}

// ---------------- final SPMM (d=40) + bias + log_softmax -> FP32 output ----------------
__global__ __launch_bounds__(256) void spmm_softmax_out(
    const float* __restrict__ s15, const int* __restrict__ cnt,
    const int2* __restrict__ ell, const unsigned short* __restrict__ bias,
    float* __restrict__ out) {
  int wave = threadIdx.x >> 6, lane = threadIdx.x & 63;
  int row = blockIdx.x * 4 + wave;
  if (row >= NN) return;
  int n = cnt[row];
  if (n > CAP) n = CAP;
  int padn = (n + 7) & ~7;
  int2 ev = make_int2(0, 0);
  if (lane < padn) ev = ell[(size_t)row * CAP + lane];
  int fl = lane < NC ? lane : NC - 1;  // keep all 64 lanes convergent for shfl
  float acc = 0.f;
  for (int j = 0; j < padn; j += 4) {
    float g[4];
    #pragma unroll
    for (int u = 0; u < 4; ++u) {
      int s = __shfl(ev.x, j + u);
      g[u] = s15[(size_t)s * NC + fl];
    }
    #pragma unroll
    for (int u = 0; u < 4; ++u) {
      union { int i; float f; } wv; wv.i = __shfl(ev.y, j + u);
      acc += wv.f * g[u];
    }
  }
  acc += bf2f(bias[fl]);
  float v = (lane < NC) ? acc : -3.0e38f;
  float m = v;
  #pragma unroll
  for (int off = 32; off > 0; off >>= 1) m = fmaxf(m, __shfl_xor(m, off));
  float e = (lane < NC) ? expf(v - m) : 0.f;
  float sum = e;
  #pragma unroll
  for (int off = 32; off > 0; off >>= 1) sum += __shfl_xor(sum, off);
  if (lane < NC) out[(size_t)row * NC + lane] = v - m - logf(sum);
}

extern "C" void kernel_launch(void* const* d_in, const int* in_sizes, int n_in,
                              void* d_out, int out_size, void* d_ws, size_t ws_size,
                              hipStream_t stream) {
  const void* x   = d_in[0];
  const int* esrc = (const int*)d_in[1];
  const int* edst = (const int*)d_in[2];
  const void* ew  = d_in[3];
  const void* W0  = d_in[4];
  const void* b0  = d_in[5];
  const void* W1  = d_in[6];
  const void* b1  = d_in[7];
  const void* Wm  = d_in[8];
  const void* bm  = d_in[9];
  const void* W15 = d_in[10];
  const void* b15 = d_in[11];
  float* out = (float*)d_out;   // reference output dtype = float32

  char* ws = (char*)d_ws;
  size_t off = 0;
  auto alloc = [&](size_t bytes) -> void* {
    void* p = ws + off;
    off = (off + bytes + 255) & ~(size_t)255;
    return p;
  };
  unsigned short* xcat = (unsigned short*)alloc((size_t)NN * KCAT * 2);  // x14|...|x1
  unsigned short* xbf  = (unsigned short*)alloc((size_t)NN * 256 * 2);
  unsigned short* supp = (unsigned short*)alloc((size_t)NN * DH * 2);
  unsigned short* zbuf = (unsigned short*)alloc((size_t)NN * DH * 2);
  float* s15           = (float*)alloc((size_t)NN * NC * 4);
  int* counts          = (int*)alloc((size_t)(NN + 1) * 4);  // [NN] = dtype wild count
  int2* ell            = (int2*)alloc((size_t)NN * CAP * 8);
  unsigned short* W01T = (unsigned short*)alloc((size_t)256 * 256 * 2);  // rows0-127=W0T,128-255=W1T
  unsigned short* WmT  = (unsigned short*)alloc((size_t)13 * 128 * 128 * 2);
  unsigned short* W15T = (unsigned short*)alloc((size_t)48 * 1792 * 2);
  unsigned short* bb   = (unsigned short*)alloc((size_t)(128 + 128 + 13 * 128 + 40) * 2);
  if (off > ws_size) return;  // signature: output stays zero
  int* flag = counts + NN;
  unsigned short* b0b  = bb;
  unsigned short* b1b  = bb + 128;
  unsigned short* bmb  = bb + 256;
  unsigned short* b15b = bb + 256 + 13 * 128;

  init_counts_detect<<<197, 256, 0, stream>>>(counts, (const unsigned short*)x);
  transpose_w<<<128, 256, 0, stream>>>(W0, W01T, 1, 256, 128, 128, flag);
  transpose_w<<<128, 256, 0, stream>>>(W1, W01T + 128 * 256, 1, 256, 128, 128, flag);
  transpose_w<<<832, 256, 0, stream>>>(Wm, WmT, 13, 128, 128, 128, flag);
  transpose_w<<<336, 256, 0, stream>>>(W15, W15T, 1, 1792, 40, 48, flag);
  convert_f4<<<2048, 256, 0, stream>>>(x, xbf, NN * 256 / 4, flag);
  convert_bias<<<8, 256, 0, stream>>>(b0, b1, bm, b15, bb, flag);
  build_ell<<<3125, 256, 0, stream>>>(esrc, edst, ew, counts, ell, flag);

  int gb64 = (NN + 63) / 64;   // 782
  int sb   = (NN + 3) / 4;     // 12500
  int gb32 = (NN + 31) / 32;   // 1563
  int ssb  = (NN / 16) * 4;    // 12500 sliced-spmm blocks (4 slices x 3125 row-blocks)
  pad_ell<<<sb, 256, 0, stream>>>(counts, ell);
  gemm_first<<<gb64, 256, 0, stream>>>(xbf, W01T, zbuf, supp, b0b);
  spmm_layer_sliced<<<ssb, 256, 0, stream>>>(supp, counts, ell, b1b, zbuf, DH,
                                             xcat + 13 * DH, KCAT);          // x1
  for (int l = 0; l < 13; ++l) {
    gemm_mid<<<gb32, 256, 0, stream>>>(xcat + (13 - l) * DH,
                                       WmT + l * 128 * 128, supp);
    spmm_layer_sliced<<<ssb, 256, 0, stream>>>(supp, counts, ell, bmb + l * DH,
                                               xcat + (13 - l) * DH, KCAT,
                                               xcat + (12 - l) * DH, KCAT);
  }
  gemm_cat4<<<gb64, 256, 0, stream>>>(xcat, W15T, s15);
  spmm_softmax_out<<<sb, 256, 0, stream>>>(s15, counts, ell, b15b, out);
}

// Round 6
// 949.457 us; speedup vs baseline: 1.1945x; 1.1945x over previous
//
#include <hip/hip_runtime.h>
#include <stdint.h>

#define NN 50000
#define EE 800000
#define DH 128
#define NC 40
#define KCAT (14*DH)   // 1792
#define CAP 64         // ELL capacity; deg ~ Binom(800k,1/50k), P(deg>64) ~ 1e-18

typedef __bf16 bf16x8 __attribute__((ext_vector_type(8)));
typedef float floatx4 __attribute__((ext_vector_type(4)));

// async global->LDS, 16B per lane, linear dest (wave-uniform base + lane*16)
#define GLOAD_LDS16(gp, lp)                                                          \
  __builtin_amdgcn_global_load_lds(                                                  \
      (const __attribute__((address_space(1))) uint32_t*)(gp),                       \
      (__attribute__((address_space(3))) uint32_t*)(lp), 16, 0, 0)

__device__ __forceinline__ float bf2f(unsigned short u) {
  union { uint32_t i; float f; } v; v.i = ((uint32_t)u) << 16; return v.f;
}
__device__ __forceinline__ unsigned short f2bf(float f) {
  union { float f; uint32_t i; } v; v.f = f;
  uint32_t x = v.i;
  uint32_t r = (x + 0x7fffu + ((x >> 16) & 1u)) >> 16;  // RNE
  return (unsigned short)r;
}

// ---------------- setup: zero ELL counts + hist + dtype detect ----------------
__global__ void init_counts_detect(int* counts, int* hist, const unsigned short* xw) {
  int i = blockIdx.x * blockDim.x + threadIdx.x;
  if (i < NN) counts[i] = 0;
  if (i < 16) hist[i] = 0;
  if (blockIdx.x == 0) {
    int t = threadIdx.x;
    int wild = 0;
    for (int k = t; k < 4096; k += 256) {
      unsigned e = (xw[k] >> 7) & 0xFF;
      if (e >= 0x90) wild++;
    }
    __shared__ int red[256];
    red[t] = wild;
    __syncthreads();
    for (int s = 128; s > 0; s >>= 1) {
      if (t < s) red[t] += red[t + s];
      __syncthreads();
    }
    if (t == 0) counts[NN] = red[0];  // flag slot
  }
}

// vectorized dtype convert (n must be divisible by 4)
__global__ void convert_f4(const void* in, unsigned short* outp, int n4, const int* flag) {
  bool isf32 = (*flag) > 32;
  for (int i = blockIdx.x * blockDim.x + threadIdx.x; i < n4;
       i += gridDim.x * blockDim.x) {
    ushort4 o;
    if (isf32) {
      float4 v = ((const float4*)in)[i];
      o.x = f2bf(v.x); o.y = f2bf(v.y); o.z = f2bf(v.z); o.w = f2bf(v.w);
    } else {
      o = ((const ushort4*)in)[i];
    }
    ((ushort4*)outp)[i] = o;
  }
}

// all four bias vectors in one launch; bb layout: b0[128] b1[128] bm[1664] b15[40]
__global__ void convert_bias(const void* b0, const void* b1, const void* bm,
                             const void* b15, unsigned short* bb, const int* flag) {
  bool isf32 = (*flag) > 32;
  int i = blockIdx.x * blockDim.x + threadIdx.x;
  if (i >= 1960) return;
  const void* src; int off;
  if (i < 128)        { src = b0;  off = i; }
  else if (i < 256)   { src = b1;  off = i - 128; }
  else if (i < 1920)  { src = bm;  off = i - 256; }
  else                { src = b15; off = i - 1920; }
  bb[i] = isf32 ? f2bf(((const float*)src)[off]) : ((const unsigned short*)src)[off];
}

// B[L][K][M] -> BT[L][Mpad][K] (bf16 out), zero-pad n>=M
__global__ void transpose_w(const void* B, unsigned short* BT,
                            int L, int K, int M, int Mpad, const int* flag) {
  bool isf32 = (*flag) > 32;
  int total = L * Mpad * K;
  for (int idx = blockIdx.x * blockDim.x + threadIdx.x; idx < total;
       idx += gridDim.x * blockDim.x) {
    int k = idx % K;
    int n = (idx / K) % Mpad;
    int l = idx / (K * Mpad);
    unsigned short v = 0;
    if (n < M) {
      size_t si = (size_t)l * K * M + (size_t)k * M + n;
      v = isf32 ? f2bf(((const float*)B)[si]) : ((const unsigned short*)B)[si];
    }
    BT[idx] = v;
  }
}

// ---------------- ELL adjacency build ----------------
__global__ void build_ell(const int* __restrict__ src, const int* __restrict__ dst,
                          const void* __restrict__ w,
                          int* __restrict__ cnt, int2* __restrict__ ell,
                          const int* __restrict__ flag) {
  bool isf32 = (*flag) > 32;
  int e = blockIdx.x * blockDim.x + threadIdx.x;
  if (e >= EE) return;
  int d = dst[e];
  if ((unsigned)d >= NN) return;
  int p = atomicAdd(&cnt[d], 1);
  if (p >= CAP) return;
  int s = src[e];
  float wf = isf32 ? ((const float*)w)[e] : bf2f(((const unsigned short*)w)[e]);
  if ((unsigned)s >= NN) { s = 0; wf = 0.f; }
  union { float f; int i; } wv; wv.f = wf;
  ell[(size_t)d * CAP + p] = make_int2(s, wv.i);
}

// pad each row's slots to a multiple of 8 with zero-weight edges
__global__ void pad_ell(const int* __restrict__ cnt, int2* __restrict__ ell) {
  int wave = threadIdx.x >> 6, lane = threadIdx.x & 63;
  int row = blockIdx.x * 4 + wave;
  if (row >= NN) return;
  int n = cnt[row];
  if (n > CAP) n = CAP;
  int padn = (n + 7) & ~7;
  if (lane >= n && lane < padn) ell[(size_t)row * CAP + lane] = make_int2(0, 0);
}

// ---------------- degree-sorted permutation (counting sort, 9 buckets) ----------
__global__ void hist_padn(const int* __restrict__ cnt, int* __restrict__ hist) {
  __shared__ int lh[9];
  int t = threadIdx.x;
  if (t < 9) lh[t] = 0;
  __syncthreads();
  int i = blockIdx.x * 256 + t;
  if (i < NN) {
    int n = cnt[i]; if (n > CAP) n = CAP;
    atomicAdd(&lh[(n + 7) >> 3], 1);
  }
  __syncthreads();
  if (t < 9 && lh[t]) atomicAdd(&hist[t], lh[t]);
}

__global__ void scan9(const int* __restrict__ hist, int* __restrict__ base) {
  if (threadIdx.x == 0) {
    int s = 0;
    for (int k = 0; k < 9; ++k) { base[k] = s; s += hist[k]; }
  }
}

__global__ void scatter_perm(const int* __restrict__ cnt, int* __restrict__ base,
                             int* __restrict__ perm) {
  __shared__ int lh[9], lbase[9];
  int t = threadIdx.x;
  if (t < 9) lh[t] = 0;
  __syncthreads();
  int i = blockIdx.x * 256 + t;
  int b = 0, p = 0;
  if (i < NN) {
    int n = cnt[i]; if (n > CAP) n = CAP;
    b = (n + 7) >> 3;
    p = atomicAdd(&lh[b], 1);
  }
  __syncthreads();
  if (t < 9) lbase[t] = lh[t] ? atomicAdd(&base[t], lh[t]) : 0;
  __syncthreads();
  if (i < NN) perm[lbase[b] + p] = i;
}

// ============ first GEMM pair: z = x@W0+b0, supp = x@W1 (K=256, 256 cols) ============
__global__ __launch_bounds__(256) void gemm_first(
    const unsigned short* __restrict__ A,    // xbf [N][256]
    const unsigned short* __restrict__ BT,   // [256][256]: rows 0-127=W0T, 128-255=W1T
    unsigned short* __restrict__ C0,         // zbuf [N][128]  (+bias)
    unsigned short* __restrict__ C1,         // supp [N][128]
    const unsigned short* __restrict__ bias) {
  __shared__ unsigned short As[64 * 256];    // 32KB, row stride 512B, swizzled
  int t = threadIdx.x;
  int wave = t >> 6, lane = t & 63;
  int q = lane >> 4, mn = lane & 15;
  int r0 = blockIdx.x * 64;

  #pragma unroll
  for (int cc = 0; cc < 8; ++cc) {
    int L = cc * 4096 + t * 16;
    int row = L >> 9;
    int colb = (L & 511) ^ ((row & 7) << 4);
    int gr = r0 + row; if (gr >= NN) gr = NN - 1;
    GLOAD_LDS16((const char*)A + (size_t)gr * 512 + colb, (char*)As + L);
  }
  __syncthreads();

  floatx4 acc[4][4];
  floatx4 zf = {0.f, 0.f, 0.f, 0.f};
  #pragma unroll
  for (int i = 0; i < 4; ++i)
    #pragma unroll
    for (int j = 0; j < 4; ++j) acc[i][j] = zf;

  #pragma unroll
  for (int ks = 0; ks < 8; ++ks) {
    bf16x8 fa[4], fb[4];
    #pragma unroll
    for (int i = 0; i < 4; ++i) {
      int row = i * 16 + mn;
      fa[i] = *(const bf16x8*)((const char*)As + row * 512 +
                               ((ks * 64 + q * 16) ^ ((row & 7) << 4)));
    }
    #pragma unroll
    for (int j = 0; j < 4; ++j)
      fb[j] = *(const bf16x8*)((const char*)BT +
                               (size_t)(wave * 64 + j * 16 + mn) * 512 + ks * 64 + q * 16);
    #pragma unroll
    for (int i = 0; i < 4; ++i)
      #pragma unroll
      for (int j = 0; j < 4; ++j)
        acc[i][j] = __builtin_amdgcn_mfma_f32_16x16x32_bf16(fa[i], fb[j], acc[i][j], 0, 0, 0);
  }

  #pragma unroll
  for (int j = 0; j < 4; ++j) {
    int col = wave * 64 + j * 16 + mn;
    bool is0 = col < 128;
    int ccol = is0 ? col : col - 128;
    unsigned short* Cp = is0 ? C0 : C1;
    float badd = is0 ? bf2f(bias[ccol]) : 0.f;
    #pragma unroll
    for (int i = 0; i < 4; ++i) {
      int rbase = r0 + i * 16 + q * 4;
      #pragma unroll
      for (int rr = 0; rr < 4; ++rr) {
        int row = rbase + rr;
        if (row < NN) Cp[(size_t)row * 128 + ccol] = f2bf(acc[i][j][rr] + badd);
      }
    }
  }
}

// ============ mid GEMM: supp[N,128] = x_l[N(,KCAT stride)][128] @ B ============
__global__ __launch_bounds__(256) void gemm_mid(
    const unsigned short* __restrict__ A,    // row stride KCAT
    const unsigned short* __restrict__ BT,   // [128][128]
    unsigned short* __restrict__ C) {        // supp [N][128]
  __shared__ unsigned short As[32 * 128];    // 8KB, row stride 256B, swizzled
  int t = threadIdx.x;
  int wave = t >> 6, lane = t & 63;
  int q = lane >> 4, mn = lane & 15;
  int r0 = blockIdx.x * 32;

  #pragma unroll
  for (int cc = 0; cc < 2; ++cc) {
    int L = cc * 4096 + t * 16;
    int row = L >> 8;
    int colb = (L & 255) ^ ((row & 7) << 4);
    int gr = r0 + row; if (gr >= NN) gr = NN - 1;
    GLOAD_LDS16((const char*)A + (size_t)gr * (KCAT * 2) + colb, (char*)As + L);
  }
  __syncthreads();

  floatx4 acc[2][2];
  floatx4 zf = {0.f, 0.f, 0.f, 0.f};
  #pragma unroll
  for (int i = 0; i < 2; ++i)
    #pragma unroll
    for (int j = 0; j < 2; ++j) acc[i][j] = zf;

  #pragma unroll
  for (int ks = 0; ks < 4; ++ks) {
    bf16x8 fa[2], fb[2];
    #pragma unroll
    for (int i = 0; i < 2; ++i) {
      int row = i * 16 + mn;
      fa[i] = *(const bf16x8*)((const char*)As + row * 256 +
                               ((ks * 64 + q * 16) ^ ((row & 7) << 4)));
    }
    #pragma unroll
    for (int j = 0; j < 2; ++j)
      fb[j] = *(const bf16x8*)((const char*)BT +
                               (size_t)(wave * 32 + j * 16 + mn) * 256 + ks * 64 + q * 16);
    #pragma unroll
    for (int i = 0; i < 2; ++i)
      #pragma unroll
      for (int j = 0; j < 2; ++j)
        acc[i][j] = __builtin_amdgcn_mfma_f32_16x16x32_bf16(fa[i], fb[j], acc[i][j], 0, 0, 0);
  }

  #pragma unroll
  for (int i = 0; i < 2; ++i) {
    int rbase = r0 + i * 16 + q * 4;
    #pragma unroll
    for (int j = 0; j < 2; ++j) {
      int col = wave * 32 + j * 16 + mn;
      #pragma unroll
      for (int rr = 0; rr < 4; ++rr) {
        int row = rbase + rr;
        if (row < NN) C[(size_t)row * 128 + col] = f2bf(acc[i][j][rr]);
      }
    }
  }
}

// ============ final GEMM: s15[N,40] = xcat[N,1792] @ W15 (fp32 out) ============
// Round-0 structure, reverted verbatim: measured 57us / 1.73 TB/s, beats all
// three gload_lds/pipelined rewrites (85-88us) on identical FETCH_SIZE.
__global__ __launch_bounds__(256) void gemm_cat(
    const unsigned short* __restrict__ A, const unsigned short* __restrict__ BT /*[48][1792]*/,
    float* __restrict__ C) {
  __shared__ unsigned short As[128][40];
  __shared__ unsigned short Bs[48][40];
  int t = threadIdx.x;
  int wave = t >> 6, lane = t & 63;
  int q = lane >> 4, mn = lane & 15;
  int r0 = blockIdx.x * 128;
  floatx4 acc[2][3];
  floatx4 zf = {0.f, 0.f, 0.f, 0.f};
  #pragma unroll
  for (int i = 0; i < 2; ++i)
    #pragma unroll
    for (int j = 0; j < 3; ++j) acc[i][j] = zf;

  int arow = t >> 2;
  int akc = (t & 3) << 3;

  for (int k0 = 0; k0 < KCAT; k0 += 32) {
    #pragma unroll
    for (int h = 0; h < 2; ++h) {
      int r = arow + h * 64;
      uint4 v = make_uint4(0, 0, 0, 0);
      if (r0 + r < NN) v = *(const uint4*)(A + (size_t)(r0 + r) * KCAT + k0 + akc);
      *(uint4*)(&As[r][akc]) = v;
    }
    if (t < 192) {
      uint4 v = *(const uint4*)(BT + (size_t)arow * KCAT + k0 + akc);
      *(uint4*)(&Bs[arow][akc]) = v;
    }
    __syncthreads();
    bf16x8 fa[2], fb[3];
    #pragma unroll
    for (int i = 0; i < 2; ++i) fa[i] = *(const bf16x8*)(&As[wave * 32 + i * 16 + mn][q * 8]);
    #pragma unroll
    for (int j = 0; j < 3; ++j) fb[j] = *(const bf16x8*)(&Bs[j * 16 + mn][q * 8]);
    #pragma unroll
    for (int i = 0; i < 2; ++i)
      #pragma unroll
      for (int j = 0; j < 3; ++j)
        acc[i][j] = __builtin_amdgcn_mfma_f32_16x16x32_bf16(fa[i], fb[j], acc[i][j], 0, 0, 0);
    __syncthreads();
  }
  #pragma unroll
  for (int i = 0; i < 2; ++i) {
    int rbase = r0 + wave * 32 + i * 16 + q * 4;
    #pragma unroll
    for (int j = 0; j < 3; ++j) {
      int col = j * 16 + mn;
      #pragma unroll
      for (int rr = 0; rr < 4; ++rr) {
        int row = rbase + rr;
        if (row < NN && col < NC) C[(size_t)row * NC + col] = acc[i][j][rr];
      }
    }
  }
}

// ---------------- SPMM fused: out = relu(agg + b) + res ----------------
// 16 lanes x 16B cover a full 256B feature row; wave = 4 independent rows
// (4x MLP, 1 gather instruction per 4 edges). Rows come from a degree-sorted
// permutation so the 4 rows sharing a wave have equal padded degree -> the
// wave-max loop does no excess work. Per-feature slot order is ascending,
// identical to previous (passing) rounds.
__global__ __launch_bounds__(256) void spmm_layer4(
    const unsigned short* __restrict__ support, const int* __restrict__ cnt,
    const int2* __restrict__ ell, const int* __restrict__ perm,
    const unsigned short* __restrict__ bias,
    const unsigned short* __restrict__ res, int res_stride,
    unsigned short* __restrict__ out, int out_stride) {
  int t = threadIdx.x;
  int wave = t >> 6, lane = t & 63;
  int g = lane >> 4, gl = lane & 15;
  int rix = blockIdx.x * 16 + wave * 4 + g;    // NN = 16*3125 exactly
  int row = perm[rix];
  int n = cnt[row]; if (n > CAP) n = CAP;
  int padn = (n + 7) & ~7;
  const int2* erow = ell + (size_t)row * CAP;
  int2 ev0 = (gl      < padn) ? erow[gl]      : make_int2(0, 0);
  int2 ev1 = (gl + 16 < padn) ? erow[gl + 16] : make_int2(0, 0);
  int2 ev2 = (gl + 32 < padn) ? erow[gl + 32] : make_int2(0, 0);
  int2 ev3 = (gl + 48 < padn) ? erow[gl + 48] : make_int2(0, 0);
  int wmax = padn;
  wmax = max(wmax, __shfl_xor(wmax, 16));
  wmax = max(wmax, __shfl_xor(wmax, 32));
  int srcbase = lane & 0x30;                   // group*16
  int colb = gl * 16;                          // byte offset in 256B feature row

  float a[8];
  #pragma unroll
  for (int e = 0; e < 8; ++e) a[e] = 0.f;
  uint4 gA[4], gB[4];

  auto load4 = [&](uint4* gbuf, int2 EV, int off) {
    #pragma unroll
    for (int u = 0; u < 4; ++u) {
      int s = __shfl(EV.x, srcbase + off + u);
      gbuf[u] = *(const uint4*)((const char*)support + (size_t)s * 256 + colb);
    }
  };
  auto fma4 = [&](const uint4* gbuf, int2 EV, int off) {
    #pragma unroll
    for (int u = 0; u < 4; ++u) {
      union { int i; float f; } wv; wv.i = __shfl(EV.y, srcbase + off + u);
      uint32_t w[4] = {gbuf[u].x, gbuf[u].y, gbuf[u].z, gbuf[u].w};
      #pragma unroll
      for (int e = 0; e < 4; ++e) {
        union { uint32_t i; float f; } lo, hi;
        lo.i = w[e] << 16;
        hi.i = w[e] & 0xffff0000u;
        a[2 * e]     += wv.f * lo.f;
        a[2 * e + 1] += wv.f * hi.f;
      }
    }
  };

  if (wmax > 0) {
    load4(gA, ev0, 0);
    /*b0 */                 load4(gB, ev0, 4);                    fma4(gA, ev0, 0);
    /*b1 */ { if (wmax >  8) load4(gA, ev0, 8);                   fma4(gB, ev0, 4); }
    if (wmax >  8) { if (wmax > 12) load4(gB, ev0, 12);           fma4(gA, ev0, 8); }
    if (wmax > 12) { if (wmax > 16) load4(gA, ev1, 0);            fma4(gB, ev0, 12); }
    if (wmax > 16) { if (wmax > 20) load4(gB, ev1, 4);            fma4(gA, ev1, 0); }
    if (wmax > 20) { if (wmax > 24) load4(gA, ev1, 8);            fma4(gB, ev1, 4); }
    if (wmax > 24) { if (wmax > 28) load4(gB, ev1, 12);           fma4(gA, ev1, 8); }
    if (wmax > 28) { if (wmax > 32) load4(gA, ev2, 0);            fma4(gB, ev1, 12); }
    if (wmax > 32) { if (wmax > 36) load4(gB, ev2, 4);            fma4(gA, ev2, 0); }
    if (wmax > 36) { if (wmax > 40) load4(gA, ev2, 8);            fma4(gB, ev2, 4); }
    if (wmax > 40) { if (wmax > 44) load4(gB, ev2, 12);           fma4(gA, ev2, 8); }
    if (wmax > 44) { if (wmax > 48) load4(gA, ev3, 0);            fma4(gB, ev2, 12); }
    if (wmax > 48) { if (wmax > 52) load4(gB, ev3, 4);            fma4(gA, ev3, 0); }
    if (wmax > 52) { if (wmax > 56) load4(gA, ev3, 8);            fma4(gB, ev3, 4); }
    if (wmax > 56) { if (wmax > 60) load4(gB, ev3, 12);           fma4(gA, ev3, 8); }
    if (wmax > 60) fma4(gB, ev3, 12);
  }

  uint4 bw = *(const uint4*)((const char*)bias + colb);
  uint4 rw = *(const uint4*)((const char*)res + (size_t)row * res_stride * 2 + colb);
  uint32_t bwa[4] = {bw.x, bw.y, bw.z, bw.w};
  uint32_t rwa[4] = {rw.x, rw.y, rw.z, rw.w};
  uint32_t ob[4];
  #pragma unroll
  for (int e = 0; e < 4; ++e) {
    union { uint32_t i; float f; } blo, bhi, rlo, rhi;
    blo.i = bwa[e] << 16; bhi.i = bwa[e] & 0xffff0000u;
    rlo.i = rwa[e] << 16; rhi.i = rwa[e] & 0xffff0000u;
    float v0 = fmaxf(a[2 * e] + blo.f, 0.f) + rlo.f;
    float v1 = fmaxf(a[2 * e + 1] + bhi.f, 0.f) + rhi.f;
    ob[e] = (uint32_t)f2bf(v0) | ((uint32_t)f2bf(v1) << 16);
  }
  uint4 ov = make_uint4(ob[0], ob[1], ob[2], ob[3]);
  *(uint4*)((char*)out + (size_t)row * out_stride * 2 + colb) = ov;
}

// ---------------- final SPMM (d=40) + bias + log_softmax -> FP32 output ----------------
__global__ __launch_bounds__(256) void spmm_softmax_out(
    const float* __restrict__ s15, const int* __restrict__ cnt,
    const int2* __restrict__ ell, const unsigned short* __restrict__ bias,
    float* __restrict__ out) {
  int wave = threadIdx.x >> 6, lane = threadIdx.x & 63;
  int row = blockIdx.x * 4 + wave;
  if (row >= NN) return;
  int n = cnt[row];
  if (n > CAP) n = CAP;
  int padn = (n + 7) & ~7;
  int2 ev = make_int2(0, 0);
  if (lane < padn) ev = ell[(size_t)row * CAP + lane];
  int fl = lane < NC ? lane : NC - 1;  // keep all 64 lanes convergent for shfl
  float acc = 0.f;
  for (int j = 0; j < padn; j += 4) {
    float g[4];
    #pragma unroll
    for (int u = 0; u < 4; ++u) {
      int s = __shfl(ev.x, j + u);
      g[u] = s15[(size_t)s * NC + fl];
    }
    #pragma unroll
    for (int u = 0; u < 4; ++u) {
      union { int i; float f; } wv; wv.i = __shfl(ev.y, j + u);
      acc += wv.f * g[u];
    }
  }
  acc += bf2f(bias[fl]);
  float v = (lane < NC) ? acc : -3.0e38f;
  float m = v;
  #pragma unroll
  for (int off = 32; off > 0; off >>= 1) m = fmaxf(m, __shfl_xor(m, off));
  float e = (lane < NC) ? expf(v - m) : 0.f;
  float sum = e;
  #pragma unroll
  for (int off = 32; off > 0; off >>= 1) sum += __shfl_xor(sum, off);
  if (lane < NC) out[(size_t)row * NC + lane] = v - m - logf(sum);
}

extern "C" void kernel_launch(void* const* d_in, const int* in_sizes, int n_in,
                              void* d_out, int out_size, void* d_ws, size_t ws_size,
                              hipStream_t stream) {
  const void* x   = d_in[0];
  const int* esrc = (const int*)d_in[1];
  const int* edst = (const int*)d_in[2];
  const void* ew  = d_in[3];
  const void* W0  = d_in[4];
  const void* b0  = d_in[5];
  const void* W1  = d_in[6];
  const void* b1  = d_in[7];
  const void* Wm  = d_in[8];
  const void* bm  = d_in[9];
  const void* W15 = d_in[10];
  const void* b15 = d_in[11];
  float* out = (float*)d_out;   // reference output dtype = float32

  char* ws = (char*)d_ws;
  size_t off = 0;
  auto alloc = [&](size_t bytes) -> void* {
    void* p = ws + off;
    off = (off + bytes + 255) & ~(size_t)255;
    return p;
  };
  unsigned short* xcat = (unsigned short*)alloc((size_t)NN * KCAT * 2);  // x14|...|x1
  unsigned short* xbf  = (unsigned short*)alloc((size_t)NN * 256 * 2);
  unsigned short* supp = (unsigned short*)alloc((size_t)NN * DH * 2);
  unsigned short* zbuf = (unsigned short*)alloc((size_t)NN * DH * 2);
  float* s15           = (float*)alloc((size_t)NN * NC * 4);
  int* counts          = (int*)alloc((size_t)(NN + 1) * 4);  // [NN] = dtype wild count
  int* perm            = (int*)alloc((size_t)NN * 4);
  int* hist            = (int*)alloc(64);                    // hist[9] + pad
  int* hbase           = (int*)alloc(64);                    // base[9] + pad
  int2* ell            = (int2*)alloc((size_t)NN * CAP * 8);
  unsigned short* W01T = (unsigned short*)alloc((size_t)256 * 256 * 2);  // rows0-127=W0T,128-255=W1T
  unsigned short* WmT  = (unsigned short*)alloc((size_t)13 * 128 * 128 * 2);
  unsigned short* W15T = (unsigned short*)alloc((size_t)48 * 1792 * 2);
  unsigned short* bb   = (unsigned short*)alloc((size_t)(128 + 128 + 13 * 128 + 40) * 2);
  if (off > ws_size) return;  // signature: output stays zero
  int* flag = counts + NN;
  unsigned short* b0b  = bb;
  unsigned short* b1b  = bb + 128;
  unsigned short* bmb  = bb + 256;
  unsigned short* b15b = bb + 256 + 13 * 128;

  init_counts_detect<<<197, 256, 0, stream>>>(counts, hist, (const unsigned short*)x);
  transpose_w<<<128, 256, 0, stream>>>(W0, W01T, 1, 256, 128, 128, flag);
  transpose_w<<<128, 256, 0, stream>>>(W1, W01T + 128 * 256, 1, 256, 128, 128, flag);
  transpose_w<<<832, 256, 0, stream>>>(Wm, WmT, 13, 128, 128, 128, flag);
  transpose_w<<<336, 256, 0, stream>>>(W15, W15T, 1, 1792, 40, 48, flag);
  convert_f4<<<2048, 256, 0, stream>>>(x, xbf, NN * 256 / 4, flag);
  convert_bias<<<8, 256, 0, stream>>>(b0, b1, bm, b15, bb, flag);
  build_ell<<<3125, 256, 0, stream>>>(esrc, edst, ew, counts, ell, flag);

  int gb64  = (NN + 63) / 64;    // 782
  int gb32  = (NN + 31) / 32;    // 1563
  int gb128 = (NN + 127) / 128;  // 391
  int sb    = (NN + 3) / 4;      // 12500
  int pb    = (NN + 255) / 256;  // 196
  int s4b   = NN / 16;           // 3125
  pad_ell<<<sb, 256, 0, stream>>>(counts, ell);
  hist_padn<<<pb, 256, 0, stream>>>(counts, hist);
  scan9<<<1, 64, 0, stream>>>(hist, hbase);
  scatter_perm<<<pb, 256, 0, stream>>>(counts, hbase, perm);
  gemm_first<<<gb64, 256, 0, stream>>>(xbf, W01T, zbuf, supp, b0b);
  spmm_layer4<<<s4b, 256, 0, stream>>>(supp, counts, ell, perm, b1b, zbuf, DH,
                                       xcat + 13 * DH, KCAT);                // x1
  for (int l = 0; l < 13; ++l) {
    gemm_mid<<<gb32, 256, 0, stream>>>(xcat + (13 - l) * DH,
                                       WmT + l * 128 * 128, supp);
    spmm_layer4<<<s4b, 256, 0, stream>>>(supp, counts, ell, perm, bmb + l * DH,
                                         xcat + (13 - l) * DH, KCAT,
                                         xcat + (12 - l) * DH, KCAT);
  }
  gemm_cat<<<gb128, 256, 0, stream>>>(xcat, W15T, s15);
  spmm_softmax_out<<<sb, 256, 0, stream>>>(s15, counts, ell, b15b, out);
}